// Round 9
// baseline (804.754 us; speedup 1.0000x reference)
//
#include <hip/hip_runtime.h>
#include <hip/hip_bf16.h>
#include <math.h>

#define TT 1024
#define KK 128
#define BB 512
#define RR 16              // sequences per block
#define NBLK (BB / RR)     // 32 blocks
#define TPB 256
#define LDST 136           // ushort stride per seq row (128 + 8 pad)

typedef float  f32x4  __attribute__((ext_vector_type(4)));
typedef short  bf16x8 __attribute__((ext_vector_type(8)));

// D.lo = bf16(lo), D.hi = bf16(hi)
__device__ __forceinline__ unsigned cvt_pk_bf16(float lo, float hi) {
    unsigned r;
    asm("v_cvt_pk_bf16_f32 %0, %1, %2" : "=v"(r) : "v"(lo), "v"(hi));
    return r;
}

// Scaled CRF forward, 16 seqs/block on the matrix pipe:
//   V'[128,16] = (E[128,128] . V[128,16]) ∘ exp(feat_t) ∘ r[seq]
// E bf16 in registers as MFMA A-fragments (2 tag-tiles x 4 k-tiles per wave).
// V bf16 in LDS [seq][frm] (double-buffered). r = rcp(V[tag0]) published via
// LDS one step late; La accumulates -log(r_t) (telescopes exactly).
// One barrier per step.
__global__ __launch_bounds__(TPB, 1)
void crf_fwd_kernel(const float* __restrict__ feats,
                    const float* __restrict__ trans,
                    float* __restrict__ out)
{
    const int bb   = blockIdx.x;
    const int tid  = threadIdx.x;
    const int lane = tid & 63;
    const int w    = tid >> 6;      // wave: tag-tiles 2w, 2w+1
    const int col  = lane & 15;     // seq within group (MFMA B/D col)
    const int kg   = lane >> 4;     // k/row subgroup (MFMA quad)
    const int seq  = bb * RR + col;

    __shared__ __align__(16) unsigned short vbuf[2][RR][LDST];
    __shared__ float rs[2][RR];
    __shared__ float sred[4][RR];

    // ---- A fragments: exp(trans) in bf16. A[tt][kt]: lane holds
    //      E[w*32 + tt*16 + col][kt*32 + kg*8 + 0..7]   (row=lane&15 layout)
    union ABu { bf16x8 v; unsigned u[4]; };
    ABu A[2][4];
    #pragma unroll
    for (int tt = 0; tt < 2; ++tt)
        #pragma unroll
        for (int kt = 0; kt < 4; ++kt) {
            const float* p = trans + (size_t)(w*32 + tt*16 + col) * KK + kt*32 + kg*8;
            float4 x = ((const float4*)p)[0];
            float4 y = ((const float4*)p)[1];
            A[tt][kt].u[0] = cvt_pk_bf16(__expf(x.x), __expf(x.y));
            A[tt][kt].u[1] = cvt_pk_bf16(__expf(x.z), __expf(x.w));
            A[tt][kt].u[2] = cvt_pk_bf16(__expf(y.x), __expf(y.y));
            A[tt][kt].u[3] = cvt_pk_bf16(__expf(y.z), __expf(y.w));
        }

    // ---- eEnd = exp(trans[END][tag]) for this lane's D tags ----
    float eE0[4], eE1[4];
    {
        const float* p0 = trans + (size_t)(KK-2)*KK + w*32 + 0*16 + kg*4;
        const float* p1 = trans + (size_t)(KK-2)*KK + w*32 + 1*16 + kg*4;
        float4 a = *(const float4*)p0;
        float4 b = *(const float4*)p1;
        eE0[0]=__expf(a.x); eE0[1]=__expf(a.y); eE0[2]=__expf(a.z); eE0[3]=__expf(a.w);
        eE1[0]=__expf(b.x); eE1[1]=__expf(b.y); eE1[2]=__expf(b.z); eE1[3]=__expf(b.w);
    }

    // ---- feat pipeline: fc = feat[t], fn = feat[t+1] (4 tags per tile) ----
    const float* f0p = feats + (size_t)seq*TT*KK + (w*32 + 0*16 + kg*4);
    const float* f1p = feats + (size_t)seq*TT*KK + (w*32 + 1*16 + kg*4);
    float4 fc0 = *(const float4*)f0p;
    float4 fc1 = *(const float4*)f1p;
    float4 fn0 = *(const float4*)(f0p + KK);
    float4 fn1 = *(const float4*)(f1p + KK);
    f0p += 2*KK; f1p += 2*KK;

    // ---- init v_0: zero ALL, barrier, then set START (fixes R8 init race) ----
    for (int i = tid; i < RR*LDST; i += TPB) (&vbuf[0][0][0])[i] = 0;
    __syncthreads();
    if (tid < RR) { vbuf[0][tid][KK-1] = 0x3F80; rs[0][tid] = 1.0f; }
    __syncthreads();

    float La = 0.0f;
    float v00=0,v01=0,v02=0,v03=0, v10=0,v11=0,v12=0,v13=0;

    for (int t = 0; t < TT; ++t) {
        const int buf = t & 1;

        // prefetch feat[t+2] (lane-private; compiler waits at use, not barrier)
        float4 f20 = {0,0,0,0}, f21 = {0,0,0,0};
        if (t + 2 < TT) { f20 = *(const float4*)f0p; f21 = *(const float4*)f1p; }
        f0p += KK; f1p += KK;

        // off-chain: exp(feat[t])
        float e00=__expf(fc0.x), e01=__expf(fc0.y), e02=__expf(fc0.z), e03=__expf(fc0.w);
        float e10=__expf(fc1.x), e11=__expf(fc1.y), e12=__expf(fc1.z), e13=__expf(fc1.w);

        // B fragments: V[kt*32 + kg*8 + 0..7][col]  (16B-aligned ds_read_b128)
        bf16x8 B0 = *(const bf16x8*)&vbuf[buf][col][0*32 + kg*8];
        bf16x8 B1 = *(const bf16x8*)&vbuf[buf][col][1*32 + kg*8];
        bf16x8 B2 = *(const bf16x8*)&vbuf[buf][col][2*32 + kg*8];
        bf16x8 B3 = *(const bf16x8*)&vbuf[buf][col][3*32 + kg*8];
        float r = rs[buf][col];

        const f32x4 z = {0.f, 0.f, 0.f, 0.f};
        f32x4 D0 = __builtin_amdgcn_mfma_f32_16x16x32_bf16(A[0][0].v, B0, z, 0, 0, 0);
        D0 = __builtin_amdgcn_mfma_f32_16x16x32_bf16(A[0][1].v, B1, D0, 0, 0, 0);
        D0 = __builtin_amdgcn_mfma_f32_16x16x32_bf16(A[0][2].v, B2, D0, 0, 0, 0);
        D0 = __builtin_amdgcn_mfma_f32_16x16x32_bf16(A[0][3].v, B3, D0, 0, 0, 0);
        f32x4 D1 = __builtin_amdgcn_mfma_f32_16x16x32_bf16(A[1][0].v, B0, z, 0, 0, 0);
        D1 = __builtin_amdgcn_mfma_f32_16x16x32_bf16(A[1][1].v, B1, D1, 0, 0, 0);
        D1 = __builtin_amdgcn_mfma_f32_16x16x32_bf16(A[1][2].v, B2, D1, 0, 0, 0);
        D1 = __builtin_amdgcn_mfma_f32_16x16x32_bf16(A[1][3].v, B3, D1, 0, 0, 0);

        // v' = D * ef * r
        v00 = D0.x * (e00*r); v01 = D0.y * (e01*r); v02 = D0.z * (e02*r); v03 = D0.w * (e03*r);
        v10 = D1.x * (e10*r); v11 = D1.y * (e11*r); v12 = D1.z * (e12*r); v13 = D1.w * (e13*r);

        // write v' as bf16: tags w*32 + tt*16 + kg*4 + 0..3 for seq col
        unsigned p00 = cvt_pk_bf16(v00, v01), p01 = cvt_pk_bf16(v02, v03);
        unsigned p10 = cvt_pk_bf16(v10, v11), p11 = cvt_pk_bf16(v12, v13);
        *(uint2*)&vbuf[buf ^ 1][col][w*32 + 0*16 + kg*4] = make_uint2(p00, p01);
        *(uint2*)&vbuf[buf ^ 1][col][w*32 + 1*16 + kg*4] = make_uint2(p10, p11);

        // lanes holding tag0 (wave 0, kg 0, reg 0) publish next scale
        if ((w | kg) == 0) rs[buf ^ 1][col] = __builtin_amdgcn_rcpf(v00);
        La -= __logf(r);

        __syncthreads();                 // the ONE barrier per step

        fc0 = fn0; fc1 = fn1; fn0 = f20; fn1 = f21;
    }

    // ---- out[seq] = La + log( sum_tag v_T[tag] * eEnd[tag] ) ----
    float S = v00*eE0[0] + v01*eE0[1] + v02*eE0[2] + v03*eE0[3]
            + v10*eE1[0] + v11*eE1[1] + v12*eE1[2] + v13*eE1[3];
    S += __shfl_xor(S, 16, 64);
    S += __shfl_xor(S, 32, 64);          // combine kg 0..3 (same seq)
    if (kg == 0) sred[w][col] = S;
    __syncthreads();
    if (tid < RR) {
        float St = sred[0][tid] + sred[1][tid] + sred[2][tid] + sred[3][tid];
        out[bb*RR + tid] = La + __logf(St);
    }
}

extern "C" void kernel_launch(void* const* d_in, const int* in_sizes, int n_in,
                              void* d_out, int out_size, void* d_ws, size_t ws_size,
                              hipStream_t stream) {
    const float* feats = (const float*)d_in[0];  // [B, T, K] f32
    const float* trans = (const float*)d_in[1];  // [K, K] f32
    float* out = (float*)d_out;                  // [B] f32

    crf_fwd_kernel<<<NBLK, TPB, 0, stream>>>(feats, trans, out);
}

// Round 11
// 787.149 us; speedup vs baseline: 1.0224x; 1.0224x over previous
//
#include <hip/hip_runtime.h>
#include <hip/hip_bf16.h>
#include <math.h>

#define TT 1024
#define KK 128
#define BB 512
#define NBLK 32
#define TPB 64
#define LN2F 0.69314718056f

typedef float  f32x4  __attribute__((ext_vector_type(4)));
typedef short  bf16x8 __attribute__((ext_vector_type(8)));

__device__ __forceinline__ unsigned cvt_pk_bf16(float lo, float hi) {
    unsigned r;
    asm("v_cvt_pk_bf16_f32 %0, %1, %2" : "=v"(r) : "v"(lo), "v"(hi));
    return r;
}
// round-to-nearest bf16 (setup only)
__device__ __forceinline__ unsigned short bf16_rtn(float f) {
    union { float f; unsigned u; } v; v.f = f;
    return (unsigned short)((v.u + 0x7FFFu + ((v.u >> 16) & 1u)) >> 16);
}

// Barrier-free scaled CRF forward. One wave = 16 sequences.
// Tag a <-> (tile tt=a>>4, row rr=a&15); k-position of tag a:
//   kpos(a) = (tt>>1)*32 + (rr>>2)*8 + (tt&1)*4 + (rr&3)   [bijective]
// With this permutation the D-output regs of step t ARE the B-input slots of
// step t+1 on the SAME lane -> no cross-lane movement, no LDS, no barriers.
// Scaling: v' = (E.v)·exp(feat - eap*ln2); esum += eap (exact for ANY eap).
// eap = clamp(ilogb(v[tag0]), -16, 48) broadcast via one off-chain bpermute;
// the clamp + fminf scrub make the recurrence unconditionally finite (kills
// the 0/denorm -> exp=inf -> 0*inf=NaN cascade; never binds in steady state).
__global__ __launch_bounds__(TPB, 1)
void crf_fwd_kernel(const float* __restrict__ feats,
                    const float* __restrict__ trans,
                    float* __restrict__ out)
{
    const int lane = threadIdx.x & 63;
    const int col  = lane & 15;     // seq within wave (MFMA col)
    const int kg   = lane >> 4;     // lane quad group
    const int seq  = blockIdx.x * 16 + col;

    // ---- A fragments: A[tt][kt] lane holds E'[tt*16+col][k=kg*8+j] where
    //      k-slot p=kt*32+kg*8+j carries frm tag (2kt+(j>>2))*16 + kg*4 + (j&3)
    union AB { bf16x8 v; unsigned u[4]; };
    AB A[8][4];
    #pragma unroll
    for (int tt = 0; tt < 8; ++tt)
        #pragma unroll
        for (int kt = 0; kt < 4; ++kt) {
            unsigned short h[8];
            #pragma unroll
            for (int j = 0; j < 8; ++j) {
                const int frm = (2*kt + (j >> 2))*16 + kg*4 + (j & 3);
                const int to  = tt*16 + col;
                h[j] = bf16_rtn(__expf(trans[to*KK + frm]));
            }
            #pragma unroll
            for (int q = 0; q < 4; ++q)
                A[tt][kt].u[q] = (unsigned)h[2*q] | ((unsigned)h[2*q+1] << 16);
        }

    // ---- D_0 = onehot(START=127): tt=7, rr=15 -> kg==3, reg 3 ----
    f32x4 D[8];
    #pragma unroll
    for (int tt = 0; tt < 8; ++tt) D[tt] = f32x4{0.f,0.f,0.f,0.f};
    if (kg == 3) D[7].w = 1.0f;

    // feat stream: lane reads tags tt*16 + kg*4 + 0..3 (8x float4 per step)
    const float* fb = feats + (size_t)seq * TT * KK + kg * 4;
    f32x4 fA[8], fB[8];
    #pragma unroll
    for (int tt = 0; tt < 8; ++tt) fA[tt] = *(const f32x4*)(fb + tt*16);
    #pragma unroll
    for (int tt = 0; tt < 8; ++tt) fB[tt] = *(const f32x4*)(fb + KK + tt*16);
    fb += 2 * KK;

    int eap = 0;     // exponent applied this step (uniform per seq)
    int esum = 0;    // exact sum of applied exponents

    auto step = [&](f32x4 (&fuse)[8], int t) {
        // B = bf16(D)  (same-lane identity, no cross-lane movement)
        AB B[4];
        #pragma unroll
        for (int kt = 0; kt < 4; ++kt) {
            B[kt].u[0] = cvt_pk_bf16(D[2*kt].x,   D[2*kt].y);
            B[kt].u[1] = cvt_pk_bf16(D[2*kt].z,   D[2*kt].w);
            B[kt].u[2] = cvt_pk_bf16(D[2*kt+1].x, D[2*kt+1].y);
            B[kt].u[3] = cvt_pk_bf16(D[2*kt+1].z, D[2*kt+1].w);
        }
        // M[tt] = sum_kt A[tt][kt] . B[kt]   (8 independent 4-chains)
        f32x4 M[8];
        #pragma unroll
        for (int tt = 0; tt < 8; ++tt) {
            f32x4 acc = {0.f,0.f,0.f,0.f};
            #pragma unroll
            for (int kt = 0; kt < 4; ++kt)
                acc = __builtin_amdgcn_mfma_f32_16x16x32_bf16(A[tt][kt].v, B[kt].v, acc, 0, 0, 0);
            M[tt] = acc;
        }
        // C = exp(feat - eap*ln2)  (scale folded into exp argument; eap
        // clamped so C is always finite and > 0)
        const float eoff = (float)eap * LN2F;
        f32x4 C[8];
        #pragma unroll
        for (int tt = 0; tt < 8; ++tt) {
            C[tt].x = __expf(fuse[tt].x - eoff);
            C[tt].y = __expf(fuse[tt].y - eoff);
            C[tt].z = __expf(fuse[tt].z - eoff);
            C[tt].w = __expf(fuse[tt].w - eoff);
        }
        esum += eap;
        // prefetch feat[t+2] into the just-freed buffer
        if (t + 2 < TT) {
            #pragma unroll
            for (int tt = 0; tt < 8; ++tt) fuse[tt] = *(const f32x4*)(fb + tt*16);
        }
        fb += KK;
        // D' = min(M*C, 1e30): v_min_f32 is IEEE minNum -> caps inf AND
        // quiets any stray NaN to a finite value (recurrence can't poison).
        #pragma unroll
        for (int tt = 0; tt < 8; ++tt) {
            D[tt].x = fminf(M[tt].x * C[tt].x, 1e30f);
            D[tt].y = fminf(M[tt].y * C[tt].y, 1e30f);
            D[tt].z = fminf(M[tt].z * C[tt].z, 1e30f);
            D[tt].w = fminf(M[tt].w * C[tt].w, 1e30f);
        }
        // next step's exponent: ilogb(D'[tag0]) from lane col (kg=0), clamped
        const int ex = (int)((__float_as_uint(D[0].x) >> 23) & 255u) - 127;
        int e = __builtin_amdgcn_ds_bpermute(col << 2, ex);
        eap = e < -16 ? -16 : (e > 48 ? 48 : e);
    };

    for (int t = 0; t < TT; t += 2) {
        step(fA, t);
        step(fB, t + 1);
    }

    // ---- out[seq] = ln2*esum + log( sum_tag D_T[tag] * exp(trans[END][tag]) )
    float S = 0.f;
    #pragma unroll
    for (int tt = 0; tt < 8; ++tt) {
        const float* pe = trans + (size_t)(KK - 2) * KK + tt*16 + kg*4;
        S += D[tt].x * __expf(pe[0]);
        S += D[tt].y * __expf(pe[1]);
        S += D[tt].z * __expf(pe[2]);
        S += D[tt].w * __expf(pe[3]);
    }
    S += __shfl_xor(S, 16, 64);
    S += __shfl_xor(S, 32, 64);
    if (lane < 16) out[seq] = LN2F * (float)esum + __logf(S);
}

extern "C" void kernel_launch(void* const* d_in, const int* in_sizes, int n_in,
                              void* d_out, int out_size, void* d_ws, size_t ws_size,
                              hipStream_t stream) {
    const float* feats = (const float*)d_in[0];  // [B, T, K] f32
    const float* trans = (const float*)d_in[1];  // [K, K] f32
    float* out = (float*)d_out;                  // [B] f32

    crf_fwd_kernel<<<NBLK, TPB, 0, stream>>>(feats, trans, out);
}

// Round 12
// 752.733 us; speedup vs baseline: 1.0691x; 1.0457x over previous
//
#include <hip/hip_runtime.h>
#include <hip/hip_bf16.h>
#include <math.h>

#define TT 1024
#define KK 128
#define BB 512
#define NBLK 32
#define TPB 64
#define LN2F 0.69314718056f

typedef float  f32x4  __attribute__((ext_vector_type(4)));
typedef short  bf16x8 __attribute__((ext_vector_type(8)));

__device__ __forceinline__ unsigned cvt_pk_bf16(float lo, float hi) {
    unsigned r;
    asm("v_cvt_pk_bf16_f32 %0, %1, %2" : "=v"(r) : "v"(lo), "v"(hi));
    return r;
}
// round-to-nearest bf16 (setup only)
__device__ __forceinline__ unsigned short bf16_rtn(float f) {
    union { float f; unsigned u; } v; v.f = f;
    return (unsigned short)((v.u + 0x7FFFu + ((v.u >> 16) & 1u)) >> 16);
}

// Barrier-free scaled CRF forward. One wave = 16 sequences.
// Tag a <-> (tile tt=a>>4, row rr=a&15); k-position of tag a:
//   kpos(a) = (tt>>1)*32 + (rr>>2)*8 + (tt&1)*4 + (rr&3)   [bijective]
// D-output regs of step t ARE the B-input slots of step t+1 on the SAME lane.
// R12 scheduling fixes vs R11:
//  - MFMA issued kt-major (8 independent accumulators between dependent uses
//    -> no per-MFMA dep-latency stall)
//  - normalizer 2^-eap applied at B-pack (exact power-of-2 mul), NOT inside
//    exp: C = exp(feat) depends only on prefetched feats -> schedules into
//    the MFMA shadow; bpermute leaves the critical path.
__global__ __launch_bounds__(TPB, 1)
void crf_fwd_kernel(const float* __restrict__ feats,
                    const float* __restrict__ trans,
                    float* __restrict__ out)
{
    const int lane = threadIdx.x & 63;
    const int col  = lane & 15;     // seq within wave (MFMA col)
    const int kg   = lane >> 4;     // lane quad group
    const int seq  = blockIdx.x * 16 + col;

    // ---- A fragments: A[tt][kt] lane holds E'[tt*16+col][k=kg*8+j] where
    //      k-slot p=kt*32+kg*8+j carries frm tag (2kt+(j>>2))*16 + kg*4 + (j&3)
    union AB { bf16x8 v; unsigned u[4]; };
    AB A[8][4];
    #pragma unroll
    for (int tt = 0; tt < 8; ++tt)
        #pragma unroll
        for (int kt = 0; kt < 4; ++kt) {
            unsigned short h[8];
            #pragma unroll
            for (int j = 0; j < 8; ++j) {
                const int frm = (2*kt + (j >> 2))*16 + kg*4 + (j & 3);
                const int to  = tt*16 + col;
                h[j] = bf16_rtn(__expf(trans[to*KK + frm]));
            }
            #pragma unroll
            for (int q = 0; q < 4; ++q)
                A[tt][kt].u[q] = (unsigned)h[2*q] | ((unsigned)h[2*q+1] << 16);
        }

    // ---- D_0 = onehot(START=127): tt=7, rr=15 -> kg==3, reg 3 ----
    f32x4 D[8];
    #pragma unroll
    for (int tt = 0; tt < 8; ++tt) D[tt] = f32x4{0.f,0.f,0.f,0.f};
    if (kg == 3) D[7].w = 1.0f;

    // feat stream: lane reads tags tt*16 + kg*4 + 0..3 (8x float4 per step)
    const float* fb = feats + (size_t)seq * TT * KK + kg * 4;
    f32x4 fA[8], fB[8];
    #pragma unroll
    for (int tt = 0; tt < 8; ++tt) fA[tt] = *(const f32x4*)(fb + tt*16);
    #pragma unroll
    for (int tt = 0; tt < 8; ++tt) fB[tt] = *(const f32x4*)(fb + KK + tt*16);
    fb += 2 * KK;

    int eap = 0;     // exponent applied at this step's B-pack (uniform per seq)
    int esum = 0;    // exact sum of applied exponents

    auto step = [&](f32x4 (&fuse)[8], int t) {
        // C = exp(feat[t]) — depends ONLY on fuse (off the serial chain)
        f32x4 C[8];
        #pragma unroll
        for (int tt = 0; tt < 8; ++tt) {
            C[tt].x = __expf(fuse[tt].x);
            C[tt].y = __expf(fuse[tt].y);
            C[tt].z = __expf(fuse[tt].z);
            C[tt].w = __expf(fuse[tt].w);
        }
        // B = bf16(D * 2^-eap)  (exact pow2 scale; same-lane identity pack)
        const float sc = __int_as_float((unsigned)(127 - eap) << 23);
        AB B[4];
        #pragma unroll
        for (int kt = 0; kt < 4; ++kt) {
            f32x4 da = D[2*kt]   * sc;
            f32x4 db = D[2*kt+1] * sc;
            B[kt].u[0] = cvt_pk_bf16(da.x, da.y);
            B[kt].u[1] = cvt_pk_bf16(da.z, da.w);
            B[kt].u[2] = cvt_pk_bf16(db.x, db.y);
            B[kt].u[3] = cvt_pk_bf16(db.z, db.w);
        }
        esum += eap;
        // M = E . B, kt-major: consecutive MFMAs independent (diff tt)
        f32x4 M[8];
        #pragma unroll
        for (int tt = 0; tt < 8; ++tt) M[tt] = f32x4{0.f,0.f,0.f,0.f};
        #pragma unroll
        for (int kt = 0; kt < 4; ++kt)
            #pragma unroll
            for (int tt = 0; tt < 8; ++tt)
                M[tt] = __builtin_amdgcn_mfma_f32_16x16x32_bf16(A[tt][kt].v, B[kt].v, M[tt], 0, 0, 0);
        // prefetch feat[t+2] into the just-freed buffer
        if (t + 2 < TT) {
            #pragma unroll
            for (int tt = 0; tt < 8; ++tt) fuse[tt] = *(const f32x4*)(fb + tt*16);
        }
        fb += KK;
        // D' = min(M*C, 1e30)  (overflow cap; min quiets a stray NaN)
        #pragma unroll
        for (int tt = 0; tt < 8; ++tt) {
            f32x4 p = M[tt] * C[tt];
            D[tt].x = fminf(p.x, 1e30f);
            D[tt].y = fminf(p.y, 1e30f);
            D[tt].z = fminf(p.z, 1e30f);
            D[tt].w = fminf(p.w, 1e30f);
        }
        // next step's exponent: ilogb(D[tag0]) from lane col (kg=0), clamped
        const int ex = (int)((__float_as_uint(D[0].x) >> 23) & 255u) - 127;
        int e = __builtin_amdgcn_ds_bpermute(col << 2, ex);
        eap = e < -16 ? -16 : (e > 48 ? 48 : e);
    };

    for (int t = 0; t < TT; t += 2) {
        step(fA, t);
        step(fB, t + 1);
    }

    // ---- out[seq] = ln2*esum + log( sum_tag D_T[tag] * exp(trans[END][tag]) )
    float S = 0.f;
    #pragma unroll
    for (int tt = 0; tt < 8; ++tt) {
        const float* pe = trans + (size_t)(KK - 2) * KK + tt*16 + kg*4;
        S += D[tt].x * __expf(pe[0]);
        S += D[tt].y * __expf(pe[1]);
        S += D[tt].z * __expf(pe[2]);
        S += D[tt].w * __expf(pe[3]);
    }
    S += __shfl_xor(S, 16, 64);
    S += __shfl_xor(S, 32, 64);
    if (lane < 16) out[seq] = LN2F * (float)esum + __logf(S);
}

extern "C" void kernel_launch(void* const* d_in, const int* in_sizes, int n_in,
                              void* d_out, int out_size, void* d_ws, size_t ws_size,
                              hipStream_t stream) {
    const float* feats = (const float*)d_in[0];  // [B, T, K] f32
    const float* trans = (const float*)d_in[1];  // [K, K] f32
    float* out = (float*)d_out;                  // [B] f32

    crf_fwd_kernel<<<NBLK, TPB, 0, stream>>>(feats, trans, out);
}

// Round 13
// 608.364 us; speedup vs baseline: 1.3228x; 1.2373x over previous
//
#include <hip/hip_runtime.h>
#include <hip/hip_bf16.h>
#include <math.h>

#define TT 1024
#define KK 128
#define BB 512
#define NBLK 32
#define TPB 192
#define NS 8            // ring slots (power of 2)
#define SSTR 164        // floats per seq row in a slot (128 + bank pad)
#define LN2F 0.69314718056f

typedef float  f32x4  __attribute__((ext_vector_type(4)));
typedef short  bf16x8 __attribute__((ext_vector_type(8)));

__device__ __forceinline__ unsigned cvt_pk_bf16(float lo, float hi) {
    unsigned r;
    asm("v_cvt_pk_bf16_f32 %0, %1, %2" : "=v"(r) : "v"(lo), "v"(hi));
    return r;
}
__device__ __forceinline__ unsigned short bf16_rtn(float f) {
    union { float f; unsigned u; } v; v.f = f;
    return (unsigned short)((v.u + 0x7FFFu + ((v.u >> 16) & 1u)) >> 16);
}
#define LGKM0() asm volatile("s_waitcnt lgkmcnt(0)" ::: "memory")

// Producer/consumer CRF forward. 32 blocks x 3 waves; 16 seqs/block.
// Waves 0-1 (producers): C_t = exp(feats[:,t,:]) -> LDS ring (f32, NS slots,
//   pad-20-per-16 layout => <=2-way bank conflicts). Monotonic per-slot ready
//   counters (atomicAdd after lgkmcnt(0)); room-check against cons.
// Wave 2 (consumer): barrier-free scaled recurrence (R12 wiring, exp deleted):
//   B = bf16(D * 2^-eap); M = E.B (32 MFMA, kt-major); D' = min(M*C, 1e30).
//   eap from ds_bpermute launched a full step earlier (stale-1; exact via esum).
// Tag a <-> (tt=a>>4, rr=a&15); kpos(a) = (tt>>1)*32+(rr>>2)*8+(tt&1)*4+(rr&3):
// D-output regs ARE next step's B-input slots on the same lane (R11/R12-verified).
__global__ __launch_bounds__(TPB, 1)
void crf_fwd_kernel(const float* __restrict__ feats,
                    const float* __restrict__ trans,
                    float* __restrict__ out)
{
    const int tid  = threadIdx.x;
    const int wv   = tid >> 6;
    const int lane = tid & 63;

    __shared__ __align__(16) float ring[NS][16][SSTR];
    __shared__ int ready[NS];
    __shared__ int cons;

    if (tid < NS) ready[tid] = 0;
    if (tid == 0) cons = -1;
    __syncthreads();     // the only full-block barrier

    if (wv < 2) {
        // ================= PRODUCER =================
        const int sl = wv * 8 + (lane >> 3);   // local seq 0..15
        const int o  = lane & 7;               // 16-tag block
        const float* fb = feats + (size_t)(blockIdx.x * 16 + sl) * TT * KK + o * 16;
        volatile int* cp = &cons;

        f32x4 A0[4], A1[4], B0[4], B1[4];
        #pragma unroll
        for (int i = 0; i < 4; ++i) {
            A0[i] = *(const f32x4*)(fb + 0 * KK + i * 4);
            A1[i] = *(const f32x4*)(fb + 1 * KK + i * 4);
            B0[i] = *(const f32x4*)(fb + 2 * KK + i * 4);
            B1[i] = *(const f32x4*)(fb + 3 * KK + i * 4);
        }

        auto emit = [&](int t, f32x4 (&R)[4]) {
            while (*cp < t - NS) {}           // room (false for t<NS: cons>=-1)
            const int s = t & (NS - 1);
            float* dst = &ring[s][sl][o * 20];
            #pragma unroll
            for (int i = 0; i < 4; ++i) {
                f32x4 e;
                e.x = __expf(R[i].x); e.y = __expf(R[i].y);
                e.z = __expf(R[i].z); e.w = __expf(R[i].w);
                *(f32x4*)(dst + i * 4) = e;
            }
            LGKM0();                          // data visible before flag
            atomicAdd(&ready[s], 1);
        };

        for (int t = 0; t < TT; t += 4) {
            emit(t + 0, A0);
            emit(t + 1, A1);
            if (t + 5 < TT) {
                #pragma unroll
                for (int i = 0; i < 4; ++i) {
                    A0[i] = *(const f32x4*)(fb + (size_t)(t + 4) * KK + i * 4);
                    A1[i] = *(const f32x4*)(fb + (size_t)(t + 5) * KK + i * 4);
                }
            }
            emit(t + 2, B0);
            emit(t + 3, B1);
            if (t + 7 < TT) {
                #pragma unroll
                for (int i = 0; i < 4; ++i) {
                    B0[i] = *(const f32x4*)(fb + (size_t)(t + 6) * KK + i * 4);
                    B1[i] = *(const f32x4*)(fb + (size_t)(t + 7) * KK + i * 4);
                }
            }
        }
        return;
    }

    // ================= CONSUMER (wave 2) =================
    const int col = lane & 15;
    const int kg  = lane >> 4;
    const int seq = blockIdx.x * 16 + col;

    union AB { bf16x8 v; unsigned u[4]; };
    AB A[8][4];
    #pragma unroll
    for (int tt = 0; tt < 8; ++tt)
        #pragma unroll
        for (int kt = 0; kt < 4; ++kt) {
            unsigned short h[8];
            #pragma unroll
            for (int j = 0; j < 8; ++j) {
                const int frm = (2*kt + (j >> 2))*16 + kg*4 + (j & 3);
                const int to  = tt*16 + col;
                h[j] = bf16_rtn(__expf(trans[to*KK + frm]));
            }
            #pragma unroll
            for (int q = 0; q < 4; ++q)
                A[tt][kt].u[q] = (unsigned)h[2*q] | ((unsigned)h[2*q+1] << 16);
        }

    f32x4 D[8];
    #pragma unroll
    for (int tt = 0; tt < 8; ++tt) D[tt] = f32x4{0.f,0.f,0.f,0.f};
    if (kg == 3) D[7].w = 1.0f;    // START = tag 127 (tt=7, rr=15)

    int eap_use = 0;   // applied at this step's B-pack (launched >=1 step ago)
    int pend    = 0;   // bpermute result in flight
    int esum    = 0;

    for (int t = 0; t < TT; ++t) {
        const int s = t & (NS - 1);
        const int target = 2 * ((t >> 3) + 1);

        int rdy = *(volatile int*)&ready[s];
        f32x4 C[8];
        #pragma unroll
        for (int tt = 0; tt < 8; ++tt)
            C[tt] = *(const f32x4*)&ring[s][col][tt*20 + kg*4];

        // B = bf16(D * 2^-eap)  (exact pow2; same-lane identity pack)
        const float sc = __int_as_float((unsigned)(127 - eap_use) << 23);
        AB B[4];
        #pragma unroll
        for (int kt = 0; kt < 4; ++kt) {
            f32x4 da = D[2*kt]   * sc;
            f32x4 db = D[2*kt+1] * sc;
            B[kt].u[0] = cvt_pk_bf16(da.x, da.y);
            B[kt].u[1] = cvt_pk_bf16(da.z, da.w);
            B[kt].u[2] = cvt_pk_bf16(db.x, db.y);
            B[kt].u[3] = cvt_pk_bf16(db.z, db.w);
        }
        esum += eap_use;

        // M = E . B, kt-major (independent consecutive MFMAs)
        f32x4 M[8];
        #pragma unroll
        for (int tt = 0; tt < 8; ++tt) M[tt] = f32x4{0.f,0.f,0.f,0.f};
        #pragma unroll
        for (int kt = 0; kt < 4; ++kt)
            #pragma unroll
            for (int tt = 0; tt < 8; ++tt)
                M[tt] = __builtin_amdgcn_mfma_f32_16x16x32_bf16(A[tt][kt].v, B[kt].v, M[tt], 0, 0, 0);

        // rare path: slot wasn't ready at step start -> spin + re-read C
        if (rdy < target) {
            while (*(volatile int*)&ready[s] < target) {}
            #pragma unroll
            for (int tt = 0; tt < 8; ++tt)
                C[tt] = *(const f32x4*)&ring[s][col][tt*20 + kg*4];
        }

        // D' = min(M*C, 1e30)  (cap inf, quiet stray NaN)
        #pragma unroll
        for (int tt = 0; tt < 8; ++tt) {
            f32x4 p = M[tt] * C[tt];
            D[tt].x = fminf(p.x, 1e30f);
            D[tt].y = fminf(p.y, 1e30f);
            D[tt].z = fminf(p.z, 1e30f);
            D[tt].w = fminf(p.w, 1e30f);
        }

        LGKM0();                              // C reads done before freeing slot
        *(volatile int*)&cons = t;

        // normalizer pipeline: consume last step's bpermute, launch this step's
        eap_use = pend < -16 ? -16 : (pend > 48 ? 48 : pend);
        const int ex = (int)((__float_as_uint(D[0].x) >> 23) & 255u) - 127;
        pend = __builtin_amdgcn_ds_bpermute(col << 2, ex);
    }

    // out[seq] = ln2*esum + log( sum_tag D_T[tag] * exp(trans[END][tag]) )
    float S = 0.f;
    #pragma unroll
    for (int tt = 0; tt < 8; ++tt) {
        const float* pe = trans + (size_t)(KK - 2) * KK + tt*16 + kg*4;
        S += D[tt].x * __expf(pe[0]);
        S += D[tt].y * __expf(pe[1]);
        S += D[tt].z * __expf(pe[2]);
        S += D[tt].w * __expf(pe[3]);
    }
    S += __shfl_xor(S, 16, 64);
    S += __shfl_xor(S, 32, 64);
    if (lane < 16) out[seq] = LN2F * (float)esum + __logf(S);
}

extern "C" void kernel_launch(void* const* d_in, const int* in_sizes, int n_in,
                              void* d_out, int out_size, void* d_ws, size_t ws_size,
                              hipStream_t stream) {
    const float* feats = (const float*)d_in[0];  // [B, T, K] f32
    const float* trans = (const float*)d_in[1];  // [K, K] f32
    float* out = (float*)d_out;                  // [B] f32

    crf_fwd_kernel<<<NBLK, TPB, 0, stream>>>(feats, trans, out);
}